// Round 2
// baseline (1163.257 us; speedup 1.0000x reference)
//
#include <hip/hip_runtime.h>
#include <hip/hip_fp16.h>
#include <cstdint>
#include <cstddef>

#define NN 50000
#define NE 800000
#define EPSV 1e-5f
#define NT32 (NE / 32)   // 25000 tiles of 32 edge rows
#define PGRID2 512       // persistent blocks for edge_fused (2/CU x 256)

typedef _Float16 f16_t;
typedef f16_t f16x8 __attribute__((ext_vector_type(8)));
typedef f16_t f16x4 __attribute__((ext_vector_type(4)));
typedef f16_t f16x2 __attribute__((ext_vector_type(2)));
typedef float f32x4 __attribute__((ext_vector_type(4)));

__device__ __forceinline__ float fast_tanh(float x) {
  float e2 = __expf(2.f * x);
  return 1.f - 2.f / (e2 + 1.f);
}
__device__ __forceinline__ float fast_sigmoid(float x) {
  return 1.f / (1.f + __expf(-x));
}

// async global->LDS (dest = wave-uniform base + lane*size, src per-lane)
__device__ __forceinline__ void async_cp16(const void* g, void* l) {
  __builtin_amdgcn_global_load_lds(
      (const __attribute__((address_space(1))) unsigned int*)g,
      (__attribute__((address_space(3))) unsigned int*)l, 16, 0, 0);
}
__device__ __forceinline__ void async_cp4(const void* g, void* l) {
  __builtin_amdgcn_global_load_lds(
      (const __attribute__((address_space(1))) unsigned int*)g,
      (__attribute__((address_space(3))) unsigned int*)l, 4, 0, 0);
}

// ---------------------------------------------------------------------------
// P layout (f16, 256 per node), "pair-swizzled" for the 8-wave edge kernel:
//   P2[node][w*32 + l16*2 + n] = (node_emb @ Wn^T + b1)[node][16w + 128n + l16]
// so lane (w,l16) gathers its (filter c, core c+128) pair with ONE f16x2 load.
// h_sw and the BN1 scale/shift use the same position convention.
// ---------------------------------------------------------------------------
__launch_bounds__(256, 4)
__global__ void node_proj(const float* __restrict__ A, const float* __restrict__ w1,
                          const float* __restrict__ b1, f16_t* __restrict__ P) {
  __shared__ f16_t Alds[128][136];
  const int tid = threadIdx.x;
  const int wave = tid >> 6;
  const int lane = tid & 63;
  const int quad = lane >> 4;
  const int l16 = lane & 15;

  int cols[4];
#pragma unroll
  for (int nt = 0; nt < 4; ++nt) cols[nt] = 16 * wave + 64 * nt + l16;

  f16x8 bfrag[4][4];  // B[k=8*quad+j][n=l16] == w1[n][k] (Wn half)
#pragma unroll
  for (int nt = 0; nt < 4; ++nt)
#pragma unroll
    for (int ks = 0; ks < 4; ++ks) {
      const float* src = w1 + (size_t)cols[nt] * 256 + ks * 32 + quad * 8;
#pragma unroll
      for (int j = 0; j < 8; ++j) bfrag[nt][ks][j] = (f16_t)src[j];
    }

  float c0[4];
#pragma unroll
  for (int nt = 0; nt < 4; ++nt) c0[nt] = b1[cols[nt]];

  const int row0 = blockIdx.x * 128;
  {
    const int r = tid >> 1, half = tid & 1;
    const int grow = row0 + r;
    f16_t* dst = &Alds[r][half * 64];
    if (grow < NN) {
      const float4* src = (const float4*)(A + (size_t)grow * 128 + half * 64);
#pragma unroll
      for (int c = 0; c < 8; ++c) {
        float4 v0 = src[2 * c], v1 = src[2 * c + 1];
        f16x8 pk = {(f16_t)v0.x, (f16_t)v0.y, (f16_t)v0.z, (f16_t)v0.w,
                    (f16_t)v1.x, (f16_t)v1.y, (f16_t)v1.z, (f16_t)v1.w};
        *(f16x8*)(dst + c * 8) = pk;
      }
    } else {
      f16x8 z = {0, 0, 0, 0, 0, 0, 0, 0};
#pragma unroll
      for (int c = 0; c < 8; ++c) *(f16x8*)(dst + c * 8) = z;
    }
  }
  __syncthreads();

#pragma unroll 1
  for (int m = 0; m < 8; ++m) {
    f16x8 afrag[4];
#pragma unroll
    for (int ks = 0; ks < 4; ++ks)
      afrag[ks] = *(const f16x8*)&Alds[m * 16 + l16][ks * 32 + quad * 8];
    f32x4 acc[4];
#pragma unroll
    for (int nt = 0; nt < 4; ++nt) acc[nt] = (f32x4){0.f, 0.f, 0.f, 0.f};
#pragma unroll
    for (int ks = 0; ks < 4; ++ks)
#pragma unroll
      for (int nt = 0; nt < 4; ++nt)
        acc[nt] = __builtin_amdgcn_mfma_f32_16x16x32_f16(
            afrag[ks], bfrag[nt][ks], acc[nt], 0, 0, 0);
    const int rbase = row0 + m * 16 + quad * 4;
#pragma unroll
    for (int reg = 0; reg < 4; ++reg) {
      int g = rbase + reg;
      if (g < NN) {
        // col 16w+64nt+l16 -> pos ((w+4nt)&7)*32 + l16*2 + ((w+4nt)>>3)
        // => slot w*32+l16*2 holds (nt0,nt2); slot (w+4)*32+l16*2 holds (nt1,nt3)
        f16x2 pA, pB;
        pA[0] = (f16_t)(acc[0][reg] + c0[0]);
        pA[1] = (f16_t)(acc[2][reg] + c0[2]);
        pB[0] = (f16_t)(acc[1][reg] + c0[1]);
        pB[1] = (f16_t)(acc[3][reg] + c0[3]);
        *(f16x2*)&P[(size_t)g * 256 + wave * 32 + l16 * 2] = pA;
        *(f16x2*)&P[(size_t)g * 256 + (wave + 4) * 32 + l16 * 2] = pB;
      }
    }
  }
}

// ---------------------------------------------------------------------------
// fused edge GEMM + BN1 stats + h-store. 8 waves x nt=2 (cols 16w+128n+l16).
// 32-row tiles, f32 edge data staged async via global_load_lds into a
// double-buffered LDS tile with XOR swizzle (inverse-swizzled global source,
// linear LDS dest, swizzled ds_read). One barrier per tile; next tile's
// stage overlaps current tile's compute.
// ---------------------------------------------------------------------------
__launch_bounds__(512, 4)
__global__ void edge_fused(const float* __restrict__ A, const float* __restrict__ w1,
                           const int* __restrict__ idx, const f16_t* __restrict__ P,
                           float* __restrict__ stats, f16_t* __restrict__ Hs,
                           int* __restrict__ ctr) {
  __shared__ float AldsF[2][4096];  // 2 x (32 rows x 128 f32) = 2 x 16 KB
  __shared__ int sIdx[2][32];
  __shared__ int s_nx[2];
  const int tid = threadIdx.x;
  const int w = tid >> 6;      // 0..7
  const int lane = tid & 63;
  const int quad = lane >> 4;
  const int l16 = lane & 15;

  int cols[2];
#pragma unroll
  for (int n = 0; n < 2; ++n) cols[n] = 16 * w + 128 * n + l16;

  f16x8 bfrag[2][4];  // We half: w1[n][128 + ks*32 + quad*8 + j]
#pragma unroll
  for (int n = 0; n < 2; ++n)
#pragma unroll
    for (int ks = 0; ks < 4; ++ks) {
      const float* src = w1 + (size_t)cols[n] * 256 + 128 + ks * 32 + quad * 8;
#pragma unroll
      for (int j = 0; j < 8; ++j) bfrag[n][ks][j] = (f16_t)src[j];
    }

  // stage source offsets (inverse swizzle): LDS slot s=2w+k, lane l covers
  // row r = 2s + (l>>5), swz-col (l&31)*16; logical col = swz ^ ((r&7)<<4)
  const int r0 = 4 * w + (lane >> 5);
  const int r1 = r0 + 2;
  const int cswz = (lane & 31) * 16;
  const int so0 = r0 * 512 + (cswz ^ ((r0 & 7) << 4));
  const int so1 = r1 * 512 + (cswz ^ ((r1 & 7) << 4));
  // read-side swizzle offset (float units): (quad*8) ^ ((l16&7)*4)
  const int xoffF = (quad * 8) ^ ((l16 & 7) << 2);

  float ssum[2] = {0.f, 0.f};
  float ssq[2] = {0.f, 0.f};

  if (tid == 0) s_nx[0] = atomicAdd(ctr, 1);
  __syncthreads();
  int t = s_nx[0];
  int p = 0;
  if (t < NT32) {
    const char* gb = (const char*)A + (size_t)t * 16384;
    async_cp16(gb + so0, (char*)&AldsF[0][0] + (2 * w + 0) * 1024);
    async_cp16(gb + so1, (char*)&AldsF[0][0] + (2 * w + 1) * 1024);
    if (w == 0 && lane < 32) async_cp4(idx + t * 32 + lane, &sIdx[0][0]);
  }

  while (t < NT32) {
    if (tid == 0) s_nx[p ^ 1] = atomicAdd(ctr, 1);
    asm volatile("s_waitcnt vmcnt(0)" ::: "memory");
    __syncthreads();  // buf p staged (all waves) + s_nx[p^1] published
    const int tn = s_nx[p ^ 1];
    if (tn < NT32) {  // stage next tile into buf p^1 (overlaps compute below)
      const char* gb = (const char*)A + (size_t)tn * 16384;
      async_cp16(gb + so0, (char*)&AldsF[p ^ 1][0] + (2 * w + 0) * 1024);
      async_cp16(gb + so1, (char*)&AldsF[p ^ 1][0] + (2 * w + 1) * 1024);
      if (w == 0 && lane < 32) async_cp4(idx + tn * 32 + lane, &sIdx[p ^ 1][0]);
    }

    const float* buf = &AldsF[p][0];
#pragma unroll
    for (int m = 0; m < 2; ++m) {
      // P gathers first (longest latency)
      int node[4];
      f16x2 pvv[4];
#pragma unroll
      for (int reg = 0; reg < 4; ++reg) {
        node[reg] = sIdx[p][m * 16 + quad * 4 + reg];
        pvv[reg] = *(const f16x2*)&P[(size_t)node[reg] * 256 + w * 32 + l16 * 2];
      }
      // A fragments: f32 LDS (swizzled) -> cvt f16
      f16x8 afr[4];
      const int rb = (m * 16 + l16) * 128;
#pragma unroll
      for (int ks = 0; ks < 4; ++ks) {
        const int fa = rb + ks * 32 + xoffF;
        float4 u = *(const float4*)&buf[fa];
        float4 v = *(const float4*)&buf[fa ^ 4];
        afr[ks] = (f16x8){(f16_t)u.x, (f16_t)u.y, (f16_t)u.z, (f16_t)u.w,
                          (f16_t)v.x, (f16_t)v.y, (f16_t)v.z, (f16_t)v.w};
      }
      f32x4 acc[2];
      acc[0] = (f32x4){0.f, 0.f, 0.f, 0.f};
      acc[1] = (f32x4){0.f, 0.f, 0.f, 0.f};
#pragma unroll
      for (int ks = 0; ks < 4; ++ks) {
        acc[0] = __builtin_amdgcn_mfma_f32_16x16x32_f16(afr[ks], bfrag[0][ks],
                                                        acc[0], 0, 0, 0);
        acc[1] = __builtin_amdgcn_mfma_f32_16x16x32_f16(afr[ks], bfrag[1][ks],
                                                        acc[1], 0, 0, 0);
      }
      const int ebase = t * 32 + m * 16 + quad * 4;
#pragma unroll
      for (int reg = 0; reg < 4; ++reg) {
        float h0 = acc[0][reg] + (float)pvv[reg][0];
        float h1 = acc[1][reg] + (float)pvv[reg][1];
        ssum[0] += h0; ssq[0] += h0 * h0;
        ssum[1] += h1; ssq[1] += h1 * h1;
        f16x2 hp = {(f16_t)h0, (f16_t)h1};
        *(f16x2*)&Hs[(size_t)(ebase + reg) * 256 + w * 32 + l16 * 2] = hp;
      }
    }
    t = tn;
    p ^= 1;
  }

#pragma unroll
  for (int n = 0; n < 2; ++n) {
    float s = ssum[n], q = ssq[n];
    s += __shfl_xor(s, 16); s += __shfl_xor(s, 32);
    q += __shfl_xor(q, 16); q += __shfl_xor(q, 32);
    if (quad == 0) {
      atomicAdd(&stats[cols[n]], s);
      atomicAdd(&stats[256 + cols[n]], q);
    }
  }
}

__global__ void finalize1(const float* __restrict__ stats, const float* __restrict__ g1,
                          const float* __restrict__ be1, float* __restrict__ st_sw) {
  int j = threadIdx.x;  // 256
  float mean = stats[j] * (1.f / NE);
  float var = stats[256 + j] * (1.f / NE) - mean * mean;
  float s = g1[j] * rsqrtf(var + EPSV);
  float t = be1[j] - mean * s;
  // col j -> pair-swizzled position
  int pos = ((j >> 4) & 7) * 32 + (j & 15) * 2 + (j >> 7);
  st_sw[pos] = s;
  st_sw[256 + pos] = t;
}

// ---------------------------------------------------------------------------
// streaming BN-apply + gated activation + packed-f16 atomic scatter.
// h_sw pairs (filter c, core c+128) adjacently: no shuffles needed.
// Thread: one f16x8 (= 4 pairs), 2 half2 atomics at cols c..c+3.
// ---------------------------------------------------------------------------
__launch_bounds__(256, 8)
__global__ void edge_apply(const f16_t* __restrict__ hsw, const int* __restrict__ idx,
                           const float* __restrict__ stw, f16_t* __restrict__ acc16) {
  const int i = blockIdx.x * 256 + threadIdx.x;  // NE*32 threads exactly
  const int e = i >> 5;
  const int k2 = i & 31;
  const int node = idx[e];
  const f16x8 h8 = *(const f16x8*)&hsw[(size_t)e * 256 + k2 * 8];
  const float4 sA = *(const float4*)&stw[8 * k2];
  const float4 sB = *(const float4*)&stw[8 * k2 + 4];
  const float4 tA = *(const float4*)&stw[256 + 8 * k2];
  const float4 tB = *(const float4*)&stw[256 + 8 * k2 + 4];
  f16x2 va, vb;
  va[0] = (f16_t)(fast_sigmoid((float)h8[0] * sA.x + tA.x) *
                  fast_tanh((float)h8[1] * sA.y + tA.y));
  va[1] = (f16_t)(fast_sigmoid((float)h8[2] * sA.z + tA.z) *
                  fast_tanh((float)h8[3] * sA.w + tA.w));
  vb[0] = (f16_t)(fast_sigmoid((float)h8[4] * sB.x + tB.x) *
                  fast_tanh((float)h8[5] * sB.y + tB.y));
  vb[1] = (f16_t)(fast_sigmoid((float)h8[6] * sB.z + tB.z) *
                  fast_tanh((float)h8[7] * sB.w + tB.w));
  const int c = 16 * (k2 >> 2) + 4 * (k2 & 3);
  f16_t* rowp = acc16 + (size_t)node * 128;
  unsafeAtomicAdd((__half2*)(rowp + c), *(__half2*)&va);
  unsafeAtomicAdd((__half2*)(rowp + c + 2), *(__half2*)&vb);
}

__global__ void bn2_stats(const f16_t* __restrict__ acc16, float* __restrict__ stats) {
  const int tid = threadIdx.x;  // 256 ; tid = ph*64 + c2
  const int c2 = tid & 63;      // half2 column pair (cols 2c2, 2c2+1)
  const int ph = tid >> 6;
  float s0 = 0.f, s1 = 0.f, q0 = 0.f, q1 = 0.f;
  for (int row = blockIdx.x * 4 + ph; row < NN; row += gridDim.x * 4) {
    f16x2 v = *(const f16x2*)&acc16[(size_t)row * 128 + 2 * c2];
    float a = (float)v[0], b = (float)v[1];
    s0 += a; q0 += a * a;
    s1 += b; q1 += b * b;
  }
  __shared__ float red[256][4];
  red[tid][0] = s0; red[tid][1] = s1; red[tid][2] = q0; red[tid][3] = q1;
  __syncthreads();
  if (ph == 0) {
    float a0 = 0.f, a1 = 0.f, b0 = 0.f, b1 = 0.f;
#pragma unroll
    for (int p = 0; p < 4; ++p) {
      a0 += red[p * 64 + c2][0]; a1 += red[p * 64 + c2][1];
      b0 += red[p * 64 + c2][2]; b1 += red[p * 64 + c2][3];
    }
    atomicAdd(&stats[2 * c2], a0);
    atomicAdd(&stats[2 * c2 + 1], a1);
    atomicAdd(&stats[128 + 2 * c2], b0);
    atomicAdd(&stats[128 + 2 * c2 + 1], b1);
  }
}

__global__ void finalize2(const float* __restrict__ stats, const float* __restrict__ g2,
                          const float* __restrict__ be2, float* __restrict__ sc) {
  int j = threadIdx.x;  // 128
  float mean = stats[j] * (1.f / NN);
  float var = stats[128 + j] * (1.f / NN) - mean * mean;
  float s = g2[j] * rsqrtf(var + EPSV);
  sc[j] = s;
  sc[128 + j] = be2[j] - mean * s;
}

__global__ void final_kernel(const float* __restrict__ node_emb, const float* __restrict__ sc,
                             const f16_t* __restrict__ acc16, float* __restrict__ out) {
  int i = blockIdx.x * blockDim.x + threadIdx.x;  // one float4 each
  if (i >= NN * 32) return;
  int c4 = i & 31;
  int row = i >> 5;
  float4 s4 = ((const float4*)sc)[c4];
  float4 h4 = ((const float4*)(sc + 128))[c4];
  float4 ne = ((const float4*)node_emb)[i];
  f16x4 cv = *(const f16x4*)&acc16[(size_t)row * 128 + c4 * 4];
  float4 r;
  r.x = fast_tanh(ne.x + (float)cv[0] * s4.x + h4.x);
  r.y = fast_tanh(ne.y + (float)cv[1] * s4.y + h4.y);
  r.z = fast_tanh(ne.z + (float)cv[2] * s4.z + h4.z);
  r.w = fast_tanh(ne.w + (float)cv[3] * s4.w + h4.w);
  ((float4*)out)[i] = r;
}

extern "C" void kernel_launch(void* const* d_in, const int* in_sizes, int n_in,
                              void* d_out, int out_size, void* d_ws, size_t ws_size,
                              hipStream_t stream) {
  (void)in_sizes; (void)n_in; (void)out_size; (void)ws_size;
  const float* node_emb = (const float*)d_in[0];
  const float* edge_emb = (const float*)d_in[1];
  const int* idx = (const int*)d_in[2];
  const float* w1 = (const float*)d_in[3];
  const float* b1 = (const float*)d_in[4];
  const float* g1 = (const float*)d_in[5];
  const float* be1 = (const float*)d_in[6];
  const float* g2 = (const float*)d_in[7];
  const float* be2 = (const float*)d_in[8];
  float* out = (float*)d_out;

  // ws layout (floats): [0,512) bn1 sum+sumsq | [512,1024) bn1 scale/shift SWZ |
  // [1024,1280) bn2 sum+sumsq | [1280,1536) bn2 scale/shift | [1536] ctr
  // byte 8192+: P2 pair-swizzled f16 (25.6 MB); f16 node accumulator (12.8 MB);
  //             h_sw pair-swizzled f16 (409.6 MB)
  float* wsf = (float*)d_ws;
  float* bn1sums = wsf;
  float* st_sw = wsf + 512;
  float* bn2sums = wsf + 1024;
  float* sc2 = wsf + 1280;
  int* ctr1 = (int*)(wsf + 1536);
  char* base = (char*)d_ws + 8192;
  f16_t* P = (f16_t*)base;
  f16_t* acc16 = (f16_t*)(base + (size_t)NN * 512);
  f16_t* hsw = (f16_t*)(base + (size_t)NN * 512 + (size_t)NN * 256);

  hipMemsetAsync(wsf, 0, 2048 * sizeof(float), stream);
  hipMemsetAsync(acc16, 0, (size_t)NN * 256, stream);

  node_proj<<<(NN + 127) / 128, 256, 0, stream>>>(node_emb, w1, b1, P);
  edge_fused<<<PGRID2, 512, 0, stream>>>(edge_emb, w1, idx, P, bn1sums, hsw, ctr1);
  finalize1<<<1, 256, 0, stream>>>(bn1sums, g1, be1, st_sw);
  edge_apply<<<NE * 32 / 256, 256, 0, stream>>>(hsw, idx, st_sw, acc16);
  bn2_stats<<<128, 256, 0, stream>>>(acc16, bn2sums);
  finalize2<<<1, 128, 0, stream>>>(bn2sums, g2, be2, sc2);
  final_kernel<<<(NN * 32 + 255) / 256, 256, 0, stream>>>(node_emb, sc2, acc16, out);
}